// Round 6
// baseline (2518.768 us; speedup 1.0000x reference)
//
#include <hip/hip_runtime.h>
#include <math.h>

#define NNODES 5000
#define NEDGES 50000
#define SEQT 12
#define NB 40000
#define NSB 157      // ceil(5000/32) node-slabs per chunked prop grid
#define ECAP 768     // staged edges per 32-node slab (avg ~320)

typedef __attribute__((ext_vector_type(8))) _Float16 half8;
typedef __attribute__((ext_vector_type(2))) _Float16 half2v;
typedef __attribute__((ext_vector_type(4))) float f32x4;

// chunked tensor layout: [node][chunk=col>>3][batch][col&7], element index:
// n*(W*8) + (col>>3)*64 + b*8 + (col&7); W=64 -> stride 512 halves, W=128 -> 1024
__device__ __forceinline__ size_t cidx64(int row, int col){
    return (size_t)(row>>3)*512 + (size_t)((col>>3)*64) + (size_t)((row&7)*8) + (col&7);
}

// ---------------- setup kernels ----------------

__global__ void count_deg_k(const int* __restrict__ ei, int* deg_out, int* deg_in){
    int e = blockIdx.x*blockDim.x + threadIdx.x;
    if (e < NEDGES){
        atomicAdd(&deg_out[ei[e]], 1);
        atomicAdd(&deg_in[ei[NEDGES + e]], 1);
    }
}

__global__ void scan_k(const int* __restrict__ deg_in, int* __restrict__ row_ptr){
    __shared__ int part[256];
    int tid = threadIdx.x;
    int base = tid*20;
    int loc[20]; int s = 0;
    for (int i=0;i<20;i++){
        int idx = base+i;
        int v = (idx < NNODES) ? deg_in[idx] : 0;
        loc[i] = s; s += v;
    }
    part[tid] = s;
    __syncthreads();
    for (int off=1; off<256; off<<=1){
        int v = (tid>=off) ? part[tid-off] : 0;
        __syncthreads();
        part[tid] += v;
        __syncthreads();
    }
    int prev = (tid==0) ? 0 : part[tid-1];
    for (int i=0;i<20;i++){
        int idx = base+i;
        if (idx < NNODES) row_ptr[idx] = prev + loc[i];
    }
    if (tid==255) row_ptr[NNODES] = part[255];
}

__global__ void fill_csr_k(const int* __restrict__ ei, const int* __restrict__ deg_out,
                           const int* __restrict__ deg_in, const int* __restrict__ row_ptr,
                           int* cursor, int* __restrict__ csr_src,
                           float* __restrict__ csr_wo, float* __restrict__ csr_wi){
    int e = blockIdx.x*blockDim.x + threadIdx.x;
    if (e >= NEDGES) return;
    int s = ei[e], d = ei[NEDGES+e];
    int pos = atomicAdd(&cursor[d], 1);
    int slot = row_ptr[d] + pos;
    csr_src[slot] = s;
    csr_wo[slot] = 1.f/(float)deg_out[s];
    csr_wi[slot] = 1.f/(float)deg_in[d];
}

// pre-pack x: Xtph[t][n*8+b][2] fp16
__global__ void prepack_x_k(const float* __restrict__ x, _Float16* __restrict__ Xtph){
    int idx = blockIdx.x*256 + threadIdx.x;
    if (idx >= SEQT*NB*2) return;
    int tt = idx / (NB*2);
    int r2 = idx - tt*(NB*2);
    int row = r2 >> 1, f = r2 & 1;
    int n = row >> 3, b = row & 7;
    Xtph[idx] = (_Float16)x[((size_t)(b*SEQT+tt)*NNODES + n)*2 + f];
}

// ---------------- weight packing (refolded basis, split fp16, ks-major B-frag) ----------------
__device__ __forceinline__ float wfetch(const float* __restrict__ W, int F, int slot, int f, int c){
    const float* p0 = W + ((size_t)0*F + f)*64 + c;
    const float* p1 = W + ((size_t)1*F + f)*64 + c;
    const float* p2 = W + ((size_t)2*F + f)*64 + c;
    const float* p3 = W + ((size_t)3*F + f)*64 + c;
    const float* p4 = W + ((size_t)4*F + f)*64 + c;
    const float* p5 = W + ((size_t)5*F + f)*64 + c;
    switch(slot){
        case 0: return *p0 + *p3 - *p2 - *p5;
        case 1: return *p1;
        case 2: return *p4;
        case 3: return 2.f * *p2;
        default: return 2.f * *p5;
    }
}

__global__ void pack_l0_k(const float* __restrict__ W, _Float16* __restrict__ wh, _Float16* __restrict__ wl){
    int idx = blockIdx.x*256 + threadIdx.x;
    if (idx >= 4*11*64) return;
    int lane = idx & 63, rest = idx >> 6;
    int ks = rest % 11, cf = rest / 11;
    int col = cf*16 + (lane & 15);
    int kb = ks*32 + ((lane>>4)<<3);
    size_t o = ((size_t)(ks*4 + cf)*64 + lane)*8;
    for (int j=0;j<8;j++){
        int k = kb + j;
        float v = 0.f;
        if (ks == 0){
            if (k < 10) v = wfetch(W, 66, k>>1, k&1, col);
        } else {
            int slot = (ks-1)>>1;
            int f = 2 + k - 32 - 64*slot;
            v = wfetch(W, 66, slot, f, col);
        }
        _Float16 hh = (_Float16)v;
        wh[o+j] = hh;
        wl[o+j] = (_Float16)(v - (float)hh);
    }
}

__global__ void pack_l1_k(const float* __restrict__ W, _Float16* __restrict__ wh, _Float16* __restrict__ wl){
    int idx = blockIdx.x*256 + threadIdx.x;
    if (idx >= 4*20*64) return;
    int lane = idx & 63, rest = idx >> 6;
    int ks = rest % 20, cf = rest / 20;
    int col = cf*16 + (lane & 15);
    int kb = ks*32 + ((lane>>4)<<3);
    int slot = ks >> 2;
    size_t o = ((size_t)(ks*4 + cf)*64 + lane)*8;
    for (int j=0;j<8;j++){
        int k = kb + j;
        int f = k - slot*128;
        float v = wfetch(W, 128, slot, f, col);
        _Float16 hh = (_Float16)v;
        wh[o+j] = hh;
        wl[o+j] = (_Float16)(v - (float)hh);
    }
}

// ---------------- chunk-affine propagation kernels ----------------
// 32 nodes/block, 256 thr (thread = nl*8+b); blockIdx low bits = chunk -> XCD affinity.
// Block-wide CSR staging (nodes consecutive -> CSR rows contiguous).

#define EDGE_STAGE_DUAL \
    __shared__ int s_src[ECAP]; __shared__ float s_wo[ECAP], s_wi[ECAP]; \
    int n0 = nsb*32; \
    int n1 = n0+32 > NNODES ? NNODES : n0+32; \
    int eb = rp[n0], ee = rp[n1]; \
    int cnt = ee-eb < ECAP ? ee-eb : ECAP; \
    for (int j=threadIdx.x; j<cnt; j+=256){ \
        s_src[j] = cs[eb+j]; s_wo[j] = cwo[eb+j]; s_wi[j] = cwi[eb+j]; \
    } \
    __syncthreads(); \
    int nl = threadIdx.x >> 3, b = threadIdx.x & 7; \
    int n = n0 + nl; \
    if (n >= NNODES) return; \
    int beg = rp[n]-eb, end = rp[n+1]-eb;

#define EDGE_STAGE_ONE \
    __shared__ int s_src[ECAP]; __shared__ float s_w[ECAP]; \
    int n0 = nsb*32; \
    int n1 = n0+32 > NNODES ? NNODES : n0+32; \
    int eb = rp[n0], ee = rp[n1]; \
    int cnt = ee-eb < ECAP ? ee-eb : ECAP; \
    for (int j=threadIdx.x; j<cnt; j+=256){ \
        s_src[j] = cs[eb+j]; s_w[j] = cw[eb+j]; \
    } \
    __syncthreads(); \
    int nl = threadIdx.x >> 3, b = threadIdx.x & 7; \
    int n = n0 + nl; \
    if (n >= NNODES) return; \
    int beg = rp[n]-eb, end = rp[n+1]-eb;

// generic dual prop, 64-wide chunked: Yo = Po S, Yi = Pi S
__global__ __launch_bounds__(256) void k_dual64c(
    const _Float16* __restrict__ S,
    _Float16* __restrict__ Yo, _Float16* __restrict__ Yi,
    const int* __restrict__ rp, const int* __restrict__ cs,
    const float* __restrict__ cwo, const float* __restrict__ cwi){
    int c = blockIdx.x & 7, nsb = blockIdx.x >> 3;
    EDGE_STAGE_DUAL
    int off = c*64 + b*8;
    float ao[8]={0,0,0,0,0,0,0,0}, ai[8]={0,0,0,0,0,0,0,0};
    for (int j=beg; j<end; ++j){
        int src; float wo, wi;
        if (j < cnt){ src=s_src[j]; wo=s_wo[j]; wi=s_wi[j]; }
        else { src=cs[eb+j]; wo=cwo[eb+j]; wi=cwi[eb+j]; }
        half8 v = *(const half8*)(S + (size_t)src*512 + off);
        #pragma unroll
        for (int e=0;e<8;e++){
            float xv=(float)v[e];
            ao[e]=fmaf(wo,xv,ao[e]); ai[e]=fmaf(wi,xv,ai[e]);
        }
    }
    half8 po, pi;
    #pragma unroll
    for (int e=0;e<8;e++){ po[e]=(_Float16)ao[e]; pi[e]=(_Float16)ai[e]; }
    *(half8*)(Yo + (size_t)n*512 + off) = po;
    *(half8*)(Yi + (size_t)n*512 + off) = pi;
}

// generic second hop, 64-wide chunked, sel in grid: U2{sel} = P{sel} T1{sel}
__global__ __launch_bounds__(256) void k_prop2_64c(
    const _Float16* __restrict__ T1o, const _Float16* __restrict__ T1i,
    _Float16* __restrict__ U2o, _Float16* __restrict__ U2i,
    const int* __restrict__ rp, const int* __restrict__ cs,
    const float* __restrict__ cwo, const float* __restrict__ cwi){
    int c = blockIdx.x & 7, sel = (blockIdx.x >> 3) & 1, nsb = blockIdx.x >> 4;
    const _Float16* S = sel ? T1i : T1o;
    _Float16* U = sel ? U2i : U2o;
    const float* cw = sel ? cwi : cwo;
    EDGE_STAGE_ONE
    int off = c*64 + b*8;
    float a[8]={0,0,0,0,0,0,0,0};
    for (int j=beg; j<end; ++j){
        int src; float w;
        if (j < cnt){ src=s_src[j]; w=s_w[j]; }
        else { src=cs[eb+j]; w=cw[eb+j]; }
        half8 v = *(const half8*)(S + (size_t)src*512 + off);
        #pragma unroll
        for (int e=0;e<8;e++) a[e]=fmaf(w,(float)v[e],a[e]);
    }
    half8 p;
    #pragma unroll
    for (int e=0;e<8;e++) p[e]=(_Float16)a[e];
    *(half8*)(U + (size_t)n*512 + off) = p;
}

// L0 first hop: h-part (h0h chunked) + x side-channel (c==0 blocks)
__global__ __launch_bounds__(256) void k_dual_l0c(
    const _Float16* __restrict__ h0h, const _Float16* __restrict__ Xt,
    _Float16* __restrict__ T1o, _Float16* __restrict__ T1i, _Float16* __restrict__ XTh,
    const int* __restrict__ rp, const int* __restrict__ cs,
    const float* __restrict__ cwo, const float* __restrict__ cwi){
    int c = blockIdx.x & 7, nsb = blockIdx.x >> 3;
    EDGE_STAGE_DUAL
    int off = c*64 + b*8;
    float ao[8]={0,0,0,0,0,0,0,0}, ai[8]={0,0,0,0,0,0,0,0};
    float ax0=0,ax1=0, ay0=0,ay1=0;
    for (int j=beg; j<end; ++j){
        int src; float wo, wi;
        if (j < cnt){ src=s_src[j]; wo=s_wo[j]; wi=s_wi[j]; }
        else { src=cs[eb+j]; wo=cwo[eb+j]; wi=cwi[eb+j]; }
        half8 v = *(const half8*)(h0h + (size_t)src*512 + off);
        #pragma unroll
        for (int e=0;e<8;e++){
            float xv=(float)v[e];
            ao[e]=fmaf(wo,xv,ao[e]); ai[e]=fmaf(wi,xv,ai[e]);
        }
        if (c == 0){
            half2v xv = *(const half2v*)(Xt + (size_t)src*16 + b*2);
            float x0=(float)xv[0], x1=(float)xv[1];
            ax0=fmaf(wo,x0,ax0); ax1=fmaf(wo,x1,ax1);
            ay0=fmaf(wi,x0,ay0); ay1=fmaf(wi,x1,ay1);
        }
    }
    half8 po, pi;
    #pragma unroll
    for (int e=0;e<8;e++){ po[e]=(_Float16)ao[e]; pi[e]=(_Float16)ai[e]; }
    *(half8*)(T1o + (size_t)n*512 + off) = po;
    *(half8*)(T1i + (size_t)n*512 + off) = pi;
    if (c == 0){
        size_t ro = (size_t)n*256 + b*8;     // chunk 0 of XTh
        XTh[ro+0] = Xt[(size_t)(n*8+b)*2+0];
        XTh[ro+1] = Xt[(size_t)(n*8+b)*2+1];
        XTh[ro+2] = (_Float16)ax0; XTh[ro+3] = (_Float16)ax1;
        XTh[ro+4] = (_Float16)ay0; XTh[ro+5] = (_Float16)ay1;
    }
}

// L0 second hop: h-part + x side-channel ((sel0,c0)->cols 6,7; (sel1,c1)->cols 8,9)
__global__ __launch_bounds__(256) void k_prop2_l0c(
    const _Float16* __restrict__ T1o, const _Float16* __restrict__ T1i,
    _Float16* __restrict__ T2o, _Float16* __restrict__ T2i, _Float16* __restrict__ XTh,
    const int* __restrict__ rp, const int* __restrict__ cs,
    const float* __restrict__ cwo, const float* __restrict__ cwi){
    int c = blockIdx.x & 7, sel = (blockIdx.x >> 3) & 1, nsb = blockIdx.x >> 4;
    const _Float16* S = sel ? T1i : T1o;
    _Float16* U = sel ? T2i : T2o;
    const float* cw = sel ? cwi : cwo;
    EDGE_STAGE_ONE
    int off = c*64 + b*8;
    bool dox = (sel == 0 && c == 0) || (sel == 1 && c == 1);
    float a[8]={0,0,0,0,0,0,0,0};
    float a0=0, a1=0;
    int xsrc_off = 2 + 2*sel;
    for (int j=beg; j<end; ++j){
        int src; float w;
        if (j < cnt){ src=s_src[j]; w=s_w[j]; }
        else { src=cs[eb+j]; w=cw[eb+j]; }
        half8 v = *(const half8*)(S + (size_t)src*512 + off);
        #pragma unroll
        for (int e=0;e<8;e++) a[e]=fmaf(w,(float)v[e],a[e]);
        if (dox){
            half2v xv = *(const half2v*)(XTh + (size_t)src*256 + b*8 + xsrc_off);
            a0=fmaf(w,(float)xv[0],a0); a1=fmaf(w,(float)xv[1],a1);
        }
    }
    half8 p;
    #pragma unroll
    for (int e=0;e<8;e++) p[e]=(_Float16)a[e];
    *(half8*)(U + (size_t)n*512 + off) = p;
    if (dox){
        int col = 6 + 2*sel;
        size_t ro = (size_t)n*256 + (size_t)((col>>3)*64) + b*8 + (col&7);
        XTh[ro]   = (_Float16)a0;
        XTh[ro+1] = (_Float16)a1;   // col 6,7 or 8,9: both within same chunk row
    }
}

// L1 first hop: [h0h | h1h] -> 128-wide T1o/T1i (16 chunks)
__global__ __launch_bounds__(256) void k_dual_l1c(
    const _Float16* __restrict__ h0h, const _Float16* __restrict__ h1h,
    _Float16* __restrict__ T1o, _Float16* __restrict__ T1i,
    const int* __restrict__ rp, const int* __restrict__ cs,
    const float* __restrict__ cwo, const float* __restrict__ cwi){
    int cc = blockIdx.x & 15, nsb = blockIdx.x >> 4;
    const _Float16* S = (cc < 8) ? h0h : h1h;
    int soff_c = (cc & 7)*64;
    EDGE_STAGE_DUAL
    int soff = soff_c + b*8;
    float ao[8]={0,0,0,0,0,0,0,0}, ai[8]={0,0,0,0,0,0,0,0};
    for (int j=beg; j<end; ++j){
        int src; float wo, wi;
        if (j < cnt){ src=s_src[j]; wo=s_wo[j]; wi=s_wi[j]; }
        else { src=cs[eb+j]; wo=cwo[eb+j]; wi=cwi[eb+j]; }
        half8 v = *(const half8*)(S + (size_t)src*512 + soff);
        #pragma unroll
        for (int e=0;e<8;e++){
            float xv=(float)v[e];
            ao[e]=fmaf(wo,xv,ao[e]); ai[e]=fmaf(wi,xv,ai[e]);
        }
    }
    half8 po, pi;
    #pragma unroll
    for (int e=0;e<8;e++){ po[e]=(_Float16)ao[e]; pi[e]=(_Float16)ai[e]; }
    size_t o = (size_t)n*1024 + cc*64 + b*8;
    *(half8*)(T1o + o) = po;
    *(half8*)(T1i + o) = pi;
}

// L1 second hop on 128-wide tensors
__global__ __launch_bounds__(256) void k_prop2_128c(
    const _Float16* __restrict__ T1o, const _Float16* __restrict__ T1i,
    _Float16* __restrict__ U2o, _Float16* __restrict__ U2i,
    const int* __restrict__ rp, const int* __restrict__ cs,
    const float* __restrict__ cwo, const float* __restrict__ cwi){
    int cc = blockIdx.x & 15, sel = (blockIdx.x >> 4) & 1, nsb = blockIdx.x >> 5;
    const _Float16* S = sel ? T1i : T1o;
    _Float16* U = sel ? U2i : U2o;
    const float* cw = sel ? cwi : cwo;
    EDGE_STAGE_ONE
    int off = cc*64 + b*8;
    float a[8]={0,0,0,0,0,0,0,0};
    for (int j=beg; j<end; ++j){
        int src; float w;
        if (j < cnt){ src=s_src[j]; w=s_w[j]; }
        else { src=cs[eb+j]; w=cw[eb+j]; }
        half8 v = *(const half8*)(S + (size_t)src*1024 + off);
        #pragma unroll
        for (int e=0;e<8;e++) a[e]=fmaf(w,(float)v[e],a[e]);
    }
    half8 p;
    #pragma unroll
    for (int e=0;e<8;e++) p[e]=(_Float16)a[e];
    *(half8*)(U + (size_t)n*1024 + off) = p;
}

// ---------------- MFMA f16 GEMM: LDS-staged B (double-buffered), 32x32 wave tiles ----------------

struct KD { const _Float16* a; int st; };   // st = per-NODE stride in halves
struct GA { KD kd[20]; };

template<int NK, int NG, int EPI>
__global__ __launch_bounds__(256) void k_gemm(GA ga,
    const _Float16* __restrict__ wh0, const _Float16* __restrict__ wl0, const float* __restrict__ b0,
    const _Float16* __restrict__ wh1, const _Float16* __restrict__ wl1, const float* __restrict__ b1,
    float* __restrict__ Z, _Float16* __restrict__ Gout,
    float* __restrict__ Hf, _Float16* __restrict__ Hh,
    const float* __restrict__ Wo, const float* __restrict__ bo,
    float* __restrict__ out, int t){
    constexpr int NT = NG*2;
    __shared__ _Float16 ldsb[2][NT*2048];
    __shared__ float spr[4][32];
    const int tid = threadIdx.x;
    const int lane = tid & 63, wv = tid >> 6, rl = lane & 15, kg = lane >> 4;
    const int m0 = blockIdx.x*64 + (wv&1)*32;
    const int cfb = (wv>>1)*2;
    const _Float16* wsrc[4] = {wh0, wl0, wh1, wl1};

    half8 srg[NT];
    half8 a0, a1, a0n, a1n;

    auto sload = [&](int ks){
        #pragma unroll
        for (int j=0;j<NT;j++)
            srg[j] = *(const half8*)(wsrc[j] + (size_t)ks*2048 + tid*8);
    };
    auto swrite = [&](int buf){
        #pragma unroll
        for (int j=0;j<NT;j++)
            *(half8*)&ldsb[buf][j*2048 + tid*8] = srg[j];
    };
    auto aload = [&](int ks, half8& x0, half8& x1){
        const _Float16* base = ga.kd[ks].a;
        const int st = ga.kd[ks].st;
        int r0 = m0 + rl, r1 = m0 + 16 + rl;
        x0 = *(const half8*)(base + (size_t)(r0>>3)*st + kg*64 + (r0&7)*8);
        x1 = *(const half8*)(base + (size_t)(r1>>3)*st + kg*64 + (r1&7)*8);
    };

    f32x4 acc[NG][2][2];
    #pragma unroll
    for (int g=0; g<NG; ++g)
        #pragma unroll
        for (int cc=0; cc<2; ++cc)
            #pragma unroll
            for (int mr=0; mr<2; ++mr){
                acc[g][cc][mr][0]=0.f; acc[g][cc][mr][1]=0.f;
                acc[g][cc][mr][2]=0.f; acc[g][cc][mr][3]=0.f;
            }

    sload(0); swrite(0);
    if (NK>1) sload(1);
    aload(0, a0, a1);
    __syncthreads();
    for (int ks=0; ks<NK; ++ks){
        const int cur = ks & 1;
        if (ks+1 < NK){ swrite(cur^1); aload(ks+1, a0n, a1n); }
        if (ks+2 < NK) sload(ks+2);
        #pragma unroll
        for (int g=0; g<NG; ++g){
            #pragma unroll
            for (int s=0; s<2; ++s){
                const int jt = g*2+s;
                #pragma unroll
                for (int cc=0; cc<2; ++cc){
                    half8 bv = *(const half8*)&ldsb[cur][jt*2048 + (cfb+cc)*512 + lane*8];
                    acc[g][cc][0] = __builtin_amdgcn_mfma_f32_16x16x32_f16(a0, bv, acc[g][cc][0], 0, 0, 0);
                    acc[g][cc][1] = __builtin_amdgcn_mfma_f32_16x16x32_f16(a1, bv, acc[g][cc][1], 0, 0, 0);
                }
            }
        }
        __syncthreads();
        a0 = a0n; a1 = a1n;
    }

    if constexpr (EPI == 0){
        #pragma unroll
        for (int cc=0; cc<2; ++cc){
            const int col = (cfb+cc)*16 + rl;
            float bzv = b0[col], brv = b1[col];
            #pragma unroll
            for (int mr=0; mr<2; ++mr)
                #pragma unroll
                for (int i=0;i<4;i++){
                    int row = m0 + mr*16 + kg*4 + i;
                    float z = 1.f/(1.f+__expf(-(acc[0][cc][mr][i] + bzv)));
                    float r = 1.f/(1.f+__expf(-(acc[NG-1][cc][mr][i] + brv)));
                    size_t ix = (size_t)row*64 + col;
                    Z[ix] = z;
                    Gout[cidx64(row,col)] = (_Float16)(Hf[ix]*r);
                }
        }
    } else {
        float pr[2][4] = {{0.f,0.f,0.f,0.f},{0.f,0.f,0.f,0.f}};
        #pragma unroll
        for (int cc=0; cc<2; ++cc){
            const int col = (cfb+cc)*16 + rl;
            float bv = b0[col];
            float wo_c = 0.f;
            if constexpr (EPI == 2) wo_c = Wo[col];
            #pragma unroll
            for (int mr=0; mr<2; ++mr)
                #pragma unroll
                for (int i=0;i<4;i++){
                    int row = m0 + mr*16 + kg*4 + i;
                    float ht = tanhf(acc[0][cc][mr][i] + bv);
                    size_t ix = (size_t)row*64 + col;
                    float z = Z[ix];
                    float hn = z*Hf[ix] + (1.f-z)*ht;
                    Hf[ix] = hn;
                    Hh[cidx64(row,col)] = (_Float16)hn;
                    if constexpr (EPI == 2) pr[mr][i] = fmaf(hn, wo_c, pr[mr][i]);
                }
        }
        if constexpr (EPI == 2){
            #pragma unroll
            for (int mr=0; mr<2; ++mr)
                #pragma unroll
                for (int i=0;i<4;i++){
                    float v = pr[mr][i];
                    v += __shfl_xor(v, 1);
                    v += __shfl_xor(v, 2);
                    v += __shfl_xor(v, 4);
                    v += __shfl_xor(v, 8);
                    if (rl == 0) spr[wv][mr*16 + kg*4 + i] = v;
                }
            __syncthreads();
            if (tid < 64){
                int r = tid;
                float v = spr[r>>5][r&31] + spr[(r>>5)|2][r&31] + bo[0];
                int row = blockIdx.x*64 + r;
                int n = row >> 3, b = row & 7;
                out[(size_t)(b*SEQT + t)*NNODES + n] = v + 0.f;
            }
        }
    }
}

// ---------------- launcher ----------------

extern "C" void kernel_launch(void* const* d_in, const int* in_sizes, int n_in,
                              void* d_out, int out_size, void* d_ws, size_t ws_size,
                              hipStream_t stream){
    (void)in_sizes; (void)n_in; (void)out_size; (void)ws_size;
    const float* x  = (const float*)d_in[0];
    const int*   ei = (const int*)d_in[1];
    const float* Wz[2] = {(const float*)d_in[2],  (const float*)d_in[8]};
    const float* bz[2] = {(const float*)d_in[3],  (const float*)d_in[9]};
    const float* Wr[2] = {(const float*)d_in[4],  (const float*)d_in[10]};
    const float* br[2] = {(const float*)d_in[5],  (const float*)d_in[11]};
    const float* Wh[2] = {(const float*)d_in[6],  (const float*)d_in[12]};
    const float* bh[2] = {(const float*)d_in[7],  (const float*)d_in[13]};
    const float* Wo = (const float*)d_in[14];
    const float* bo = (const float*)d_in[15];
    float* out = (float*)d_out;

    char* p = (char*)d_ws;
    auto alloc = [&](size_t bytes)->char*{
        char* r = p; p += (bytes + 255) & ~(size_t)255; return r;
    };
    const size_t H64  = (size_t)NB*64*2;
    const size_t H128 = (size_t)NB*128*2;
    const size_t F64  = (size_t)NB*64*4;

    _Float16* Xtph = (_Float16*)alloc((size_t)SEQT*NB*2*2);
    float*    h0f = (float*)alloc(F64);
    float*    h1f = (float*)alloc(F64);
    float*    Z0  = (float*)alloc(F64);
    float*    Z1  = (float*)alloc(F64);
    _Float16* h0h = (_Float16*)alloc(H64);
    _Float16* h1h = (_Float16*)alloc(H64);
    _Float16* XTh = (_Float16*)alloc((size_t)NB*32*2);
    _Float16* Th1o = (_Float16*)alloc(H64);
    _Float16* Th1i = (_Float16*)alloc(H64);
    _Float16* Th2o = (_Float16*)alloc(H64);
    _Float16* Th2i = (_Float16*)alloc(H64);
    _Float16* G0L0 = (_Float16*)alloc(H64);
    _Float16* G1o0 = (_Float16*)alloc(H64);
    _Float16* G1i0 = (_Float16*)alloc(H64);
    _Float16* G2o0 = (_Float16*)alloc(H64);
    _Float16* G2i0 = (_Float16*)alloc(H64);
    _Float16* T1o128 = (_Float16*)alloc(H128);
    _Float16* T1i128 = (_Float16*)alloc(H128);
    _Float16* U2o128 = (_Float16*)alloc(H128);
    _Float16* U2i128 = (_Float16*)alloc(H128);
    _Float16* G0p  = (_Float16*)alloc(H64);
    _Float16* G1o1 = (_Float16*)alloc(H64);
    _Float16* G1i1 = (_Float16*)alloc(H64);
    _Float16* G2o1 = (_Float16*)alloc(H64);
    _Float16* G2i1 = (_Float16*)alloc(H64);
    _Float16 *whl0[3][2], *whl1[3][2];
    for (int g=0; g<3; ++g){
        whl0[g][0] = (_Float16*)alloc((size_t)4*11*64*8*2);
        whl0[g][1] = (_Float16*)alloc((size_t)4*11*64*8*2);
        whl1[g][0] = (_Float16*)alloc((size_t)4*20*64*8*2);
        whl1[g][1] = (_Float16*)alloc((size_t)4*20*64*8*2);
    }
    int* deg_out = (int*)alloc(NNODES*4);
    int* deg_in  = (int*)alloc(NNODES*4);
    int* row_ptr = (int*)alloc((NNODES+1)*4);
    int* cursor  = (int*)alloc(NNODES*4);
    int* csr_src = (int*)alloc(NEDGES*4);
    float* csr_wo = (float*)alloc(NEDGES*4);
    float* csr_wi = (float*)alloc(NEDGES*4);

    hipMemsetAsync(deg_out, 0, NNODES*4, stream);
    hipMemsetAsync(deg_in,  0, NNODES*4, stream);
    hipMemsetAsync(cursor,  0, NNODES*4, stream);
    hipMemsetAsync(h0f, 0, F64, stream);
    hipMemsetAsync(h1f, 0, F64, stream);
    hipMemsetAsync(h0h, 0, H64, stream);
    hipMemsetAsync(h1h, 0, H64, stream);
    hipMemsetAsync(XTh, 0, (size_t)NB*32*2, stream);

    count_deg_k<<<(NEDGES+255)/256, 256, 0, stream>>>(ei, deg_out, deg_in);
    scan_k<<<1, 256, 0, stream>>>(deg_in, row_ptr);
    fill_csr_k<<<(NEDGES+255)/256, 256, 0, stream>>>(ei, deg_out, deg_in, row_ptr,
                                                     cursor, csr_src, csr_wo, csr_wi);
    prepack_x_k<<<(SEQT*NB*2+255)/256, 256, 0, stream>>>(x, Xtph);
    const float* Wptr0[3] = {Wz[0], Wr[0], Wh[0]};
    const float* Wptr1[3] = {Wz[1], Wr[1], Wh[1]};
    for (int g=0; g<3; ++g){
        pack_l0_k<<<(4*11*64+255)/256, 256, 0, stream>>>(Wptr0[g], whl0[g][0], whl0[g][1]);
        pack_l1_k<<<(4*20*64+255)/256, 256, 0, stream>>>(Wptr1[g], whl1[g][0], whl1[g][1]);
    }

    GA gaL0zr = {}, gaL0h = {}, gaL1zr = {}, gaL1h = {};
    {
        const _Float16* t64[5] = {h0h, Th1o, Th1i, Th2o, Th2i};
        gaL0zr.kd[0] = {XTh, 256};
        for (int s=0; s<5; ++s){
            gaL0zr.kd[1+2*s] = {t64[s], 512};
            gaL0zr.kd[2+2*s] = {t64[s]+256, 512};
        }
        const _Float16* g64[5] = {G0L0, G1o0, G1i0, G2o0, G2i0};
        gaL0h.kd[0] = {XTh, 256};
        for (int s=0; s<5; ++s){
            gaL0h.kd[1+2*s] = {g64[s], 512};
            gaL0h.kd[2+2*s] = {g64[s]+256, 512};
        }
        gaL1zr.kd[0] = {h0h, 512};      gaL1zr.kd[1] = {h0h+256, 512};
        gaL1zr.kd[2] = {h1h, 512};      gaL1zr.kd[3] = {h1h+256, 512};
        const _Float16* t128[4] = {T1o128, T1i128, U2o128, U2i128};
        for (int s=0; s<4; ++s)
            for (int q=0; q<4; ++q)
                gaL1zr.kd[4+4*s+q] = {t128[s]+q*256, 1024};
        gaL1h.kd[0] = {h0h, 512};  gaL1h.kd[1] = {h0h+256, 512};
        gaL1h.kd[2] = {G0p, 512};  gaL1h.kd[3] = {G0p+256, 512};
        const _Float16* gh[4] = {G1o1, G1i1, G2o1, G2i1};
        for (int s=0; s<4; ++s){
            gaL1h.kd[4+4*s+0] = {t128[s], 1024};
            gaL1h.kd[4+4*s+1] = {t128[s]+256, 1024};
            gaL1h.kd[4+4*s+2] = {gh[s], 512};
            gaL1h.kd[4+4*s+3] = {gh[s]+256, 512};
        }
    }

    for (int t=0; t<SEQT; ++t){
        // ---- layer 0 ----
        k_dual_l0c<<<NSB*8, 256, 0, stream>>>(h0h, Xtph + (size_t)t*NB*2, Th1o, Th1i, XTh,
                                              row_ptr, csr_src, csr_wo, csr_wi);
        k_prop2_l0c<<<NSB*16, 256, 0, stream>>>(Th1o, Th1i, Th2o, Th2i, XTh,
                                                row_ptr, csr_src, csr_wo, csr_wi);
        k_gemm<11,2,0><<<NB/64, 256, 0, stream>>>(gaL0zr,
            whl0[0][0], whl0[0][1], bz[0], whl0[1][0], whl0[1][1], br[0],
            Z0, G0L0, h0f, nullptr, nullptr, nullptr, nullptr, 0);
        k_dual64c<<<NSB*8, 256, 0, stream>>>(G0L0, G1o0, G1i0, row_ptr, csr_src, csr_wo, csr_wi);
        k_prop2_64c<<<NSB*16, 256, 0, stream>>>(G1o0, G1i0, G2o0, G2i0,
                                                row_ptr, csr_src, csr_wo, csr_wi);
        k_gemm<11,1,1><<<NB/64, 256, 0, stream>>>(gaL0h,
            whl0[2][0], whl0[2][1], bh[0], nullptr, nullptr, nullptr,
            Z0, nullptr, h0f, h0h, nullptr, nullptr, nullptr, 0);
        // ---- layer 1 ----
        k_dual_l1c<<<NSB*16, 256, 0, stream>>>(h0h, h1h, T1o128, T1i128,
                                               row_ptr, csr_src, csr_wo, csr_wi);
        k_prop2_128c<<<NSB*32, 256, 0, stream>>>(T1o128, T1i128, U2o128, U2i128,
                                                 row_ptr, csr_src, csr_wo, csr_wi);
        k_gemm<20,2,0><<<NB/64, 256, 0, stream>>>(gaL1zr,
            whl1[0][0], whl1[0][1], bz[1], whl1[1][0], whl1[1][1], br[1],
            Z1, G0p, h1f, nullptr, nullptr, nullptr, nullptr, 0);
        k_dual64c<<<NSB*8, 256, 0, stream>>>(G0p, G1o1, G1i1, row_ptr, csr_src, csr_wo, csr_wi);
        k_prop2_64c<<<NSB*16, 256, 0, stream>>>(G1o1, G1i1, G2o1, G2i1,
                                                row_ptr, csr_src, csr_wo, csr_wi);
        k_gemm<20,1,2><<<NB/64, 256, 0, stream>>>(gaL1h,
            whl1[2][0], whl1[2][1], bh[1], nullptr, nullptr, nullptr,
            Z1, nullptr, h1f, h1h, Wo, bo, out, t);
    }
}